// Round 6
// baseline (2760.436 us; speedup 1.0000x reference)
//
#include <hip/hip_runtime.h>
#include <hip/hip_bf16.h>

#define TT 512
#define BB 64
#define EE 512
#define HH 1024
#define HB (BB * HH)

typedef __attribute__((ext_vector_type(8))) short short8;
typedef __attribute__((ext_vector_type(4))) float f32x4;
typedef __attribute__((ext_vector_type(4))) unsigned int u32x4;

// workspace layout (bytes)
//  X      : [T][B][E] bf16             = 33,554,432
//  Wt     : [256 ct][48 kk][512] bf16  = 12,582,912   (MFMA B-frag order)
//  hbuf   : u32[4][B][H] tagged words  =  1,048,576   ([tag16|bf16], tag=t+1)
//  probe  : [16] int                   =         64
#define WS_X     0
#define WS_WT    33554432
#define WS_HBUF  46137344
#define WS_PROBE 48496640

static __device__ __forceinline__ unsigned short f2bf(float x) {
    unsigned int u = __float_as_uint(x);
    unsigned int r = (u + 0x7fffu + ((u >> 16) & 1u)) >> 16;
    return (unsigned short)r;
}

// ---------------- embedding gather -> bf16 X[t][b][e] ----------------
__global__ void embed_k(const int* __restrict__ src, const float* __restrict__ emb,
                        unsigned short* __restrict__ X) {
    int idx  = blockIdx.x * 256 + threadIdx.x;   // one float4 per thread
    int base = idx * 4;                          // = t*32768 + b*512 + e
    int t = base >> 15;
    int r = base & 32767;
    int b = r >> 9;
    int e = r & 511;
    int v = src[b * TT + t];
    float4 f = *(const float4*)(emb + (size_t)v * EE + e);
    ushort4 s;
    s.x = f2bf(f.x); s.y = f2bf(f.y); s.z = f2bf(f.z); s.w = f2bf(f.w);
    *(ushort4*)(X + base) = s;
}

// ------- weight transpose/convert into MFMA B-fragment order -------
// Wt[((ct*48+kk)*64+lane)*8+j] = Wcomb[k = kk*32+(lane>>4)*8+j][col = ct*16+(lane&15)]
__global__ void wprep_k(const float* __restrict__ Wih, const float* __restrict__ Whh,
                        unsigned short* __restrict__ Wt, int* __restrict__ probe) {
    const int bid = blockIdx.x;          // = ct*48 + kk
    const int kk  = bid % 48;
    const int ct  = bid / 48;
    const int tid = threadIdx.x;

    // diagnostic probe (harmless, validated): asm idioms execute fine
    if (bid == 0 && tid == 0) {
        int xcd;
        asm volatile("s_getreg_b32 %0, hwreg(HW_REG_XCC_ID)" : "=s"(xcd));
        int* pr = probe;
        asm volatile("global_store_dword %0, %1, off sc0"
                     :: "v"(pr), "v"(xcd) : "memory");
        int v;
        asm volatile("global_load_dword %0, %1, off sc0\n\ts_waitcnt vmcnt(0)"
                     : "=v"(v) : "v"(pr) : "memory");
        pr[1] = v;
    }

    const int k0 = kk * 32, c0 = ct * 16;
    __shared__ float tile[32][17];
    for (int e = tid; e < 512; e += 256) {
        int kr = e >> 4, cc = e & 15;
        int k = k0 + kr;
        float v = (k < EE) ? Wih[(size_t)k * 4096 + c0 + cc]
                           : Whh[(size_t)(k - EE) * 4096 + c0 + cc];
        tile[kr][cc] = v;
    }
    __syncthreads();
    for (int e = tid; e < 512; e += 256) {
        int lane = e >> 3, j = e & 7;
        float v = tile[(lane >> 4) * 8 + j][lane & 15];
        Wt[(size_t)bid * 512 + e] = f2bf(v);
    }
}

// ---------------- persistent recurrent kernel ----------------
// 256 WGs = 4 row-groups (16 batch rows) x 64 col-groups (16 hidden units).
// Weights resident in VGPR/AGPR: wave w holds kk = 4i+w (i=0..11) x 4 gates.
// v7: TAGGED-WORD exchange on a DEPTH-4 ring. h travels as u32 [tag16|bf16],
// tag = t+1. Consumers data-poll buf[(t+3)&3] for tag==t: detect + load =
// ONE LLC RTT, no flags, no ack drain, no ring maintenance. Producers store
// buf[t&3] fire-and-forget. Overwrite of tag-(s-2) words at step s+1 is
// THREE transitive sync layers behind the readers (depth-4 slack, vs v6's
// zero-slack depth-2): producer at s+1 needs h(s) <= peers' poll(s) done <=
// peers' h(s-1) <= polls(s-1) done <= readers of tag s-2 long finished.
// Zero-init is tag-consistent (tag0|bf16 0 = h(-1)=0 passes tg=0 at t=0),
// so one uniform poll path. zred double-buffered -> single lgkmcnt+s_barrier
// per step, no __syncthreads in the loop (v5-validated skeleton).
__global__ __launch_bounds__(256, 1) void lstm_k(
    const unsigned short* __restrict__ X,
    const unsigned short* __restrict__ Wt,
    const float* __restrict__ bias,
    unsigned int* __restrict__ hbuf,
    float* __restrict__ out)
{
    const int g        = blockIdx.x;
    const int cg       = g & 63;
    const int rg       = g >> 6;
    const int row_base = rg * 16;
    const int ubase    = cg * 16;
    const int tid  = threadIdx.x;
    const int wave = tid >> 6;
    const int lane = tid & 63;
    const int lrow = lane & 15;
    const int quad = lane >> 4;
    const int erow = tid >> 4, eu = tid & 15;

    __shared__ float zred[2][4][4][16][17];   // [t&1][wave][gate][m-row][n-col]

    // bias in registers: gate layout b[g*HH + unit]
    const float bi_ = bias[          ubase + eu];
    const float bf_ = bias[HH      + ubase + eu];
    const float bg_ = bias[2 * HH  + ubase + eu];
    const float bo_ = bias[3 * HH  + ubase + eu];

    // resident weight fragments
    short8 wr[12][4];
#pragma unroll
    for (int i = 0; i < 12; ++i) {
        const int kk = i * 4 + wave;
#pragma unroll
        for (int g4 = 0; g4 < 4; ++g4) {
            const int ct = g4 * 64 + cg;
            wr[i][g4] = *(const short8*)(Wt + ((size_t)(ct * 48 + kk)) * 512 + lane * 8);
        }
    }

    // per-thread persistent cell state: thread owns (row = tid>>4, u = tid&15)
    float creg = 0.f;

    for (int t = 0; t < TT; ++t) {
        // ---- issue x loads (plain cached); drained by the poll's vmcnt(0) ----
        const unsigned short* xp = X + ((size_t)(t * BB) + row_base + lrow) * EE + quad * 8;
        short8 ax[4];
#pragma unroll
        for (int i = 0; i < 4; ++i)
            asm volatile("global_load_dwordx4 %0, %1, off"
                         : "=v"(ax[i]) : "v"(xp + (i * 4 + wave) * 32) : "memory");

        // ---- tagged data-poll of h(t-1) from ring buf[(t+3)&3], tg = t ----
        // wave w, fragment i covers h-units 128*i + 32*w + quad*8 .. +8
        const unsigned int* hb = hbuf + ((size_t)((t + 3) & 3)) * HB
                               + (size_t)(row_base + lrow) * HH + 32 * wave + quad * 8;
        u32x4 hv[16];
        {
            const unsigned int tg = (unsigned int)t;   // producers wrote (t-1)+1 = t
            while (true) {
#pragma unroll
                for (int i = 0; i < 8; ++i) {
                    const unsigned int* p = hb + 128 * i;
                    asm volatile("global_load_dwordx4 %0, %1, off sc1"
                                 : "=v"(hv[2 * i]) : "v"(p) : "memory");
                    asm volatile("global_load_dwordx4 %0, %1, off sc1"
                                 : "=v"(hv[2 * i + 1]) : "v"(p + 4) : "memory");
                }
                asm volatile("s_waitcnt vmcnt(0)" ::: "memory");
                __builtin_amdgcn_sched_barrier(0);
                unsigned int bad = 0;
#pragma unroll
                for (int k = 0; k < 16; ++k) {
                    bad |= (hv[k].x >> 16) ^ tg;
                    bad |= (hv[k].y >> 16) ^ tg;
                    bad |= (hv[k].z >> 16) ^ tg;
                    bad |= (hv[k].w >> 16) ^ tg;
                }
                if (__all(bad == 0)) break;
            }
            __builtin_amdgcn_sched_barrier(0);
        }

        // ---- pack tagged words -> bf16 A-fragments ----
        short8 ah[8];
#pragma unroll
        for (int i = 0; i < 8; ++i) {
            union { unsigned int u[4]; short8 v; } pk;
            pk.u[0] = (hv[2 * i].x & 0xFFFFu)     | (hv[2 * i].y << 16);
            pk.u[1] = (hv[2 * i].z & 0xFFFFu)     | (hv[2 * i].w << 16);
            pk.u[2] = (hv[2 * i + 1].x & 0xFFFFu) | (hv[2 * i + 1].y << 16);
            pk.u[3] = (hv[2 * i + 1].z & 0xFFFFu) | (hv[2 * i + 1].w << 16);
            ah[i] = pk.v;
        }

        f32x4 acc0 = {0.f,0.f,0.f,0.f}, acc1 = {0.f,0.f,0.f,0.f};
        f32x4 acc2 = {0.f,0.f,0.f,0.f}, acc3 = {0.f,0.f,0.f,0.f};

        // ---- x-part: kk = 0..15 ----
#pragma unroll
        for (int i = 0; i < 4; ++i) {
            acc0 = __builtin_amdgcn_mfma_f32_16x16x32_bf16(ax[i], wr[i][0], acc0, 0, 0, 0);
            acc1 = __builtin_amdgcn_mfma_f32_16x16x32_bf16(ax[i], wr[i][1], acc1, 0, 0, 0);
            acc2 = __builtin_amdgcn_mfma_f32_16x16x32_bf16(ax[i], wr[i][2], acc2, 0, 0, 0);
            acc3 = __builtin_amdgcn_mfma_f32_16x16x32_bf16(ax[i], wr[i][3], acc3, 0, 0, 0);
        }

        // ---- h-part: kk = 16..47 ----
#pragma unroll
        for (int i = 0; i < 8; ++i) {
            acc0 = __builtin_amdgcn_mfma_f32_16x16x32_bf16(ah[i], wr[i + 4][0], acc0, 0, 0, 0);
            acc1 = __builtin_amdgcn_mfma_f32_16x16x32_bf16(ah[i], wr[i + 4][1], acc1, 0, 0, 0);
            acc2 = __builtin_amdgcn_mfma_f32_16x16x32_bf16(ah[i], wr[i + 4][2], acc2, 0, 0, 0);
            acc3 = __builtin_amdgcn_mfma_f32_16x16x32_bf16(ah[i], wr[i + 4][3], acc3, 0, 0, 0);
        }

        // ---- cross-wave K reduction via LDS (double-buffered, one barrier) ----
        const int zb = t & 1;
#pragma unroll
        for (int r = 0; r < 4; ++r) {
            zred[zb][wave][0][quad * 4 + r][lrow] = acc0[r];
            zred[zb][wave][1][quad * 4 + r][lrow] = acc1[r];
            zred[zb][wave][2][quad * 4 + r][lrow] = acc2[r];
            zred[zb][wave][3][quad * 4 + r][lrow] = acc3[r];
        }
        asm volatile("s_waitcnt lgkmcnt(0)" ::: "memory");
        asm volatile("s_barrier" ::: "memory");

        // ---- gates / cell update (identical arithmetic to passed version) ----
        float zi = zred[zb][0][0][erow][eu] + zred[zb][1][0][erow][eu]
                 + zred[zb][2][0][erow][eu] + zred[zb][3][0][erow][eu] + bi_;
        float zf = zred[zb][0][1][erow][eu] + zred[zb][1][1][erow][eu]
                 + zred[zb][2][1][erow][eu] + zred[zb][3][1][erow][eu] + bf_;
        float zg = zred[zb][0][2][erow][eu] + zred[zb][1][2][erow][eu]
                 + zred[zb][2][2][erow][eu] + zred[zb][3][2][erow][eu] + bg_;
        float zo = zred[zb][0][3][erow][eu] + zred[zb][1][3][erow][eu]
                 + zred[zb][2][3][erow][eu] + zred[zb][3][3][erow][eu] + bo_;
        float iv = 1.f / (1.f + __expf(-zi));
        float fv = 1.f / (1.f + __expf(-zf));
        float gv = 1.f - 2.f / (__expf(2.f * zg) + 1.f);
        float ov = 1.f / (1.f + __expf(-zo));
        float c  = fv * creg + iv * gv;
        creg = c;
        float th = 1.f - 2.f / (__expf(2.f * c) + 1.f);
        float h  = ov * th;

        if (t < TT - 1) {
            // one tagged 4B store per thread (coalesced 64B/row); FIRE & forget
            unsigned int wv = (unsigned int)f2bf(h)
                            | (((unsigned int)(t + 1) & 0xFFFFu) << 16);
            unsigned int* hw = hbuf + (size_t)(t & 3) * HB
                             + (size_t)(row_base + erow) * HH + ubase + eu;
            asm volatile("global_store_dword %0, %1, off sc1"
                         :: "v"(hw), "v"(wv) : "memory");
        } else {
            out[(row_base + erow) * HH + ubase + eu] = h;             // h_T
            out[BB * HH + (row_base + erow) * HH + ubase + eu] = c;   // c_T
        }
        // no end-of-step barrier: zred double-buffered; depth-4 ring WAR
        // safety has three transitive layers of slack (see header).
    }
}

extern "C" void kernel_launch(void* const* d_in, const int* in_sizes, int n_in,
                              void* d_out, int out_size, void* d_ws, size_t ws_size,
                              hipStream_t stream) {
    const int*   src  = (const int*)d_in[0];
    const float* emb  = (const float*)d_in[1];
    const float* Wih  = (const float*)d_in[2];
    const float* Whh  = (const float*)d_in[3];
    const float* bias = (const float*)d_in[4];
    float* out = (float*)d_out;

    char* ws = (char*)d_ws;
    unsigned short* X     = (unsigned short*)(ws + WS_X);
    unsigned short* Wt    = (unsigned short*)(ws + WS_WT);
    unsigned int*   hbuf  = (unsigned int*)(ws + WS_HBUF);
    int*            probe = (int*)(ws + WS_PROBE);

    // all 4 ring buffers zero: word 0 = [tag 0 | bf16 0] = h(-1)=0, matches tg=0
    hipMemsetAsync(hbuf, 0, (size_t)4 * HB * 4, stream);
    embed_k<<<dim3(16384), dim3(256), 0, stream>>>(src, emb, X);
    wprep_k<<<dim3(12288), dim3(256), 0, stream>>>(Wih, Whh, Wt, probe);
    lstm_k<<<dim3(256), dim3(256), 0, stream>>>(X, Wt, bias, hbuf, out);
}

// Round 7
// 2530.088 us; speedup vs baseline: 1.0910x; 1.0910x over previous
//
#include <hip/hip_runtime.h>
#include <hip/hip_bf16.h>

#define TT 512
#define BB 64
#define EE 512
#define HH 1024
#define HB (BB * HH)

typedef __attribute__((ext_vector_type(8))) short short8;
typedef __attribute__((ext_vector_type(4))) float f32x4;
typedef __attribute__((ext_vector_type(4))) unsigned int u32x4;

// workspace layout (bytes)
//  X      : [T][B][E] bf16             = 33,554,432
//  Wt     : [256 ct][48 kk][512] bf16  = 12,582,912   (MFMA B-frag order)
//  hbuf   : u32[4][B][H] tagged words  =  1,048,576   ([tag16|bf16], tag=t+1)
//  probe  : [16] int                   =         64
#define WS_X     0
#define WS_WT    33554432
#define WS_HBUF  46137344
#define WS_PROBE 48496640

static __device__ __forceinline__ unsigned short f2bf(float x) {
    unsigned int u = __float_as_uint(x);
    unsigned int r = (u + 0x7fffu + ((u >> 16) & 1u)) >> 16;
    return (unsigned short)r;
}

// ---------------- embedding gather -> bf16 X[t][b][e] ----------------
__global__ void embed_k(const int* __restrict__ src, const float* __restrict__ emb,
                        unsigned short* __restrict__ X) {
    int idx  = blockIdx.x * 256 + threadIdx.x;   // one float4 per thread
    int base = idx * 4;                          // = t*32768 + b*512 + e
    int t = base >> 15;
    int r = base & 32767;
    int b = r >> 9;
    int e = r & 511;
    int v = src[b * TT + t];
    float4 f = *(const float4*)(emb + (size_t)v * EE + e);
    ushort4 s;
    s.x = f2bf(f.x); s.y = f2bf(f.y); s.z = f2bf(f.z); s.w = f2bf(f.w);
    *(ushort4*)(X + base) = s;
}

// ------- weight transpose/convert into MFMA B-fragment order -------
// Wt[((ct*48+kk)*64+lane)*8+j] = Wcomb[k = kk*32+(lane>>4)*8+j][col = ct*16+(lane&15)]
__global__ void wprep_k(const float* __restrict__ Wih, const float* __restrict__ Whh,
                        unsigned short* __restrict__ Wt, int* __restrict__ probe) {
    const int bid = blockIdx.x;          // = ct*48 + kk
    const int kk  = bid % 48;
    const int ct  = bid / 48;
    const int tid = threadIdx.x;

    // diagnostic probe (harmless, validated): asm idioms execute fine
    if (bid == 0 && tid == 0) {
        int xcd;
        asm volatile("s_getreg_b32 %0, hwreg(HW_REG_XCC_ID)" : "=s"(xcd));
        int* pr = probe;
        asm volatile("global_store_dword %0, %1, off sc0"
                     :: "v"(pr), "v"(xcd) : "memory");
        int v;
        asm volatile("global_load_dword %0, %1, off sc0\n\ts_waitcnt vmcnt(0)"
                     : "=v"(v) : "v"(pr) : "memory");
        pr[1] = v;
    }

    const int k0 = kk * 32, c0 = ct * 16;
    __shared__ float tile[32][17];
    for (int e = tid; e < 512; e += 256) {
        int kr = e >> 4, cc = e & 15;
        int k = k0 + kr;
        float v = (k < EE) ? Wih[(size_t)k * 4096 + c0 + cc]
                           : Whh[(size_t)(k - EE) * 4096 + c0 + cc];
        tile[kr][cc] = v;
    }
    __syncthreads();
    for (int e = tid; e < 512; e += 256) {
        int lane = e >> 3, j = e & 7;
        float v = tile[(lane >> 4) * 8 + j][lane & 15];
        Wt[(size_t)bid * 512 + e] = f2bf(v);
    }
}

// ---------------- persistent recurrent kernel ----------------
// 256 WGs = 4 row-groups (16 batch rows) x 64 col-groups (16 hidden units).
// Weights resident in VGPR/AGPR: wave w holds kk = 4i+w (i=0..11) x 4 gates.
// v8: HINT + TAG-VERIFY exchange on the depth-4 tagged ring (v7-validated
// mechanism). Producers fire tagged u32 [t+1|bf16] stores, no drain/flag/
// barrier. Consumers first spin NARROW (one 4B word per producer; the 4
// quad-lanes of each producer cover one row from each of its 4 waves), then
// bulk-load all h-words ONCE and verify tags (retry rare: a producer's
// stores issue back-to-back so arrival is clustered). This keeps v4's cheap
// spin traffic while removing v4's producer drain + flag-visibility RTTs.
// WAR safety: depth-4 ring + v6/v7 transitive induction (producer's step-s+2
// overwrite is ordered behind all peers' completed verifies of those words,
// with 2 epochs of extra slack). zred double-buffered -> one barrier/step.
__global__ __launch_bounds__(256, 1) void lstm_k(
    const unsigned short* __restrict__ X,
    const unsigned short* __restrict__ Wt,
    const float* __restrict__ bias,
    unsigned int* __restrict__ hbuf,
    float* __restrict__ out)
{
    const int g        = blockIdx.x;
    const int cg       = g & 63;
    const int rg       = g >> 6;
    const int row_base = rg * 16;
    const int ubase    = cg * 16;
    const int tid  = threadIdx.x;
    const int wave = tid >> 6;
    const int lane = tid & 63;
    const int lrow = lane & 15;
    const int quad = lane >> 4;
    const int erow = tid >> 4, eu = tid & 15;

    __shared__ float zred[2][4][4][16][17];   // [t&1][wave][gate][m-row][n-col]

    // bias in registers: gate layout b[g*HH + unit]
    const float bi_ = bias[          ubase + eu];
    const float bf_ = bias[HH      + ubase + eu];
    const float bg_ = bias[2 * HH  + ubase + eu];
    const float bo_ = bias[3 * HH  + ubase + eu];

    // resident weight fragments
    short8 wr[12][4];
#pragma unroll
    for (int i = 0; i < 12; ++i) {
        const int kk = i * 4 + wave;
#pragma unroll
        for (int g4 = 0; g4 < 4; ++g4) {
            const int ct = g4 * 64 + cg;
            wr[i][g4] = *(const short8*)(Wt + ((size_t)(ct * 48 + kk)) * 512 + lane * 8);
        }
    }

    // ---- hint-poll mapping: wave w's h-fragments cover unit blocks
    // (4i+w)*32, i=0..7 -> 16 producers cg = 8i+2w, 8i+2w+1.
    // lane -> producer via pidx=lane&15; the 4 quad-lanes of a producer
    // hint on rows {a, 4+a, 8+a, 12+a} (a=pidx&3): one row per producer wave.
    const int pidx = lane & 15;
    const int prod = 8 * (pidx >> 1) + 2 * wave + (pidx & 1);
    const int hintrow = quad * 4 + (pidx & 3);
    const int hintu   = prod * 16 + (pidx >> 2);

    // per-thread persistent cell state: thread owns (row = tid>>4, u = tid&15)
    float creg = 0.f;

    for (int t = 0; t < TT; ++t) {
        // ---- issue x loads (plain cached); drained by the verify's vmcnt(0) ----
        const unsigned short* xp = X + ((size_t)(t * BB) + row_base + lrow) * EE + quad * 8;
        short8 ax[4];
#pragma unroll
        for (int i = 0; i < 4; ++i)
            asm volatile("global_load_dwordx4 %0, %1, off"
                         : "=v"(ax[i]) : "v"(xp + (i * 4 + wave) * 32) : "memory");

        const size_t rbase = ((size_t)((t + 3) & 3)) * HB;   // ring slot holding h(t-1)
        const unsigned int tg = (unsigned int)t;             // expected tag

        // ---- NARROW hint spin: 4B/lane, per-lane divergent exit (v4-style) ----
        {
            const unsigned int* hp = hbuf + rbase
                                   + (size_t)(row_base + hintrow) * HH + hintu;
            while ((__hip_atomic_load(hp, __ATOMIC_RELAXED,
                                      __HIP_MEMORY_SCOPE_AGENT) >> 16) != tg) { }
        }

        // ---- bulk load + tag VERIFY (typically exactly one round) ----
        const unsigned int* hb = hbuf + rbase
                               + (size_t)(row_base + lrow) * HH + 32 * wave + quad * 8;
        u32x4 hv[16];
        while (true) {
#pragma unroll
            for (int i = 0; i < 8; ++i) {
                const unsigned int* p = hb + 128 * i;
                asm volatile("global_load_dwordx4 %0, %1, off sc1"
                             : "=v"(hv[2 * i]) : "v"(p) : "memory");
                asm volatile("global_load_dwordx4 %0, %1, off sc1"
                             : "=v"(hv[2 * i + 1]) : "v"(p + 4) : "memory");
            }
            asm volatile("s_waitcnt vmcnt(0)" ::: "memory");
            __builtin_amdgcn_sched_barrier(0);
            unsigned int bad = 0;
#pragma unroll
            for (int k = 0; k < 16; ++k) {
                bad |= (hv[k].x >> 16) ^ tg;
                bad |= (hv[k].y >> 16) ^ tg;
                bad |= (hv[k].z >> 16) ^ tg;
                bad |= (hv[k].w >> 16) ^ tg;
            }
            if (__all(bad == 0)) break;
        }
        __builtin_amdgcn_sched_barrier(0);

        // ---- pack tagged words -> bf16 A-fragments ----
        short8 ah[8];
#pragma unroll
        for (int i = 0; i < 8; ++i) {
            union { unsigned int u[4]; short8 v; } pk;
            pk.u[0] = (hv[2 * i].x & 0xFFFFu)     | (hv[2 * i].y << 16);
            pk.u[1] = (hv[2 * i].z & 0xFFFFu)     | (hv[2 * i].w << 16);
            pk.u[2] = (hv[2 * i + 1].x & 0xFFFFu) | (hv[2 * i + 1].y << 16);
            pk.u[3] = (hv[2 * i + 1].z & 0xFFFFu) | (hv[2 * i + 1].w << 16);
            ah[i] = pk.v;
        }

        f32x4 acc0 = {0.f,0.f,0.f,0.f}, acc1 = {0.f,0.f,0.f,0.f};
        f32x4 acc2 = {0.f,0.f,0.f,0.f}, acc3 = {0.f,0.f,0.f,0.f};

        // ---- x-part: kk = 0..15 ----
#pragma unroll
        for (int i = 0; i < 4; ++i) {
            acc0 = __builtin_amdgcn_mfma_f32_16x16x32_bf16(ax[i], wr[i][0], acc0, 0, 0, 0);
            acc1 = __builtin_amdgcn_mfma_f32_16x16x32_bf16(ax[i], wr[i][1], acc1, 0, 0, 0);
            acc2 = __builtin_amdgcn_mfma_f32_16x16x32_bf16(ax[i], wr[i][2], acc2, 0, 0, 0);
            acc3 = __builtin_amdgcn_mfma_f32_16x16x32_bf16(ax[i], wr[i][3], acc3, 0, 0, 0);
        }

        // ---- h-part: kk = 16..47 ----
#pragma unroll
        for (int i = 0; i < 8; ++i) {
            acc0 = __builtin_amdgcn_mfma_f32_16x16x32_bf16(ah[i], wr[i + 4][0], acc0, 0, 0, 0);
            acc1 = __builtin_amdgcn_mfma_f32_16x16x32_bf16(ah[i], wr[i + 4][1], acc1, 0, 0, 0);
            acc2 = __builtin_amdgcn_mfma_f32_16x16x32_bf16(ah[i], wr[i + 4][2], acc2, 0, 0, 0);
            acc3 = __builtin_amdgcn_mfma_f32_16x16x32_bf16(ah[i], wr[i + 4][3], acc3, 0, 0, 0);
        }

        // ---- cross-wave K reduction via LDS (double-buffered, one barrier) ----
        const int zb = t & 1;
#pragma unroll
        for (int r = 0; r < 4; ++r) {
            zred[zb][wave][0][quad * 4 + r][lrow] = acc0[r];
            zred[zb][wave][1][quad * 4 + r][lrow] = acc1[r];
            zred[zb][wave][2][quad * 4 + r][lrow] = acc2[r];
            zred[zb][wave][3][quad * 4 + r][lrow] = acc3[r];
        }
        asm volatile("s_waitcnt lgkmcnt(0)" ::: "memory");
        asm volatile("s_barrier" ::: "memory");

        // ---- gates / cell update (identical arithmetic to passed version) ----
        float zi = zred[zb][0][0][erow][eu] + zred[zb][1][0][erow][eu]
                 + zred[zb][2][0][erow][eu] + zred[zb][3][0][erow][eu] + bi_;
        float zf = zred[zb][0][1][erow][eu] + zred[zb][1][1][erow][eu]
                 + zred[zb][2][1][erow][eu] + zred[zb][3][1][erow][eu] + bf_;
        float zg = zred[zb][0][2][erow][eu] + zred[zb][1][2][erow][eu]
                 + zred[zb][2][2][erow][eu] + zred[zb][3][2][erow][eu] + bg_;
        float zo = zred[zb][0][3][erow][eu] + zred[zb][1][3][erow][eu]
                 + zred[zb][2][3][erow][eu] + zred[zb][3][3][erow][eu] + bo_;
        float iv = 1.f / (1.f + __expf(-zi));
        float fv = 1.f / (1.f + __expf(-zf));
        float gv = 1.f - 2.f / (__expf(2.f * zg) + 1.f);
        float ov = 1.f / (1.f + __expf(-zo));
        float c  = fv * creg + iv * gv;
        creg = c;
        float th = 1.f - 2.f / (__expf(2.f * c) + 1.f);
        float h  = ov * th;

        if (t < TT - 1) {
            // one tagged 4B store per thread (coalesced 64B/row); FIRE & forget
            unsigned int wv = (unsigned int)f2bf(h)
                            | (((unsigned int)(t + 1) & 0xFFFFu) << 16);
            unsigned int* hw = hbuf + (size_t)(t & 3) * HB
                             + (size_t)(row_base + erow) * HH + ubase + eu;
            asm volatile("global_store_dword %0, %1, off sc1"
                         :: "v"(hw), "v"(wv) : "memory");
        } else {
            out[(row_base + erow) * HH + ubase + eu] = h;             // h_T
            out[BB * HH + (row_base + erow) * HH + ubase + eu] = c;   // c_T
        }
        // no end-of-step barrier: zred double-buffered; depth-4 ring WAR
        // safety via transitive verify ordering (see header).
    }
}

extern "C" void kernel_launch(void* const* d_in, const int* in_sizes, int n_in,
                              void* d_out, int out_size, void* d_ws, size_t ws_size,
                              hipStream_t stream) {
    const int*   src  = (const int*)d_in[0];
    const float* emb  = (const float*)d_in[1];
    const float* Wih  = (const float*)d_in[2];
    const float* Whh  = (const float*)d_in[3];
    const float* bias = (const float*)d_in[4];
    float* out = (float*)d_out;

    char* ws = (char*)d_ws;
    unsigned short* X     = (unsigned short*)(ws + WS_X);
    unsigned short* Wt    = (unsigned short*)(ws + WS_WT);
    unsigned int*   hbuf  = (unsigned int*)(ws + WS_HBUF);
    int*            probe = (int*)(ws + WS_PROBE);

    // all 4 ring buffers zero: word 0 = [tag 0 | bf16 0] = h(-1)=0, matches tg=0
    hipMemsetAsync(hbuf, 0, (size_t)4 * HB * 4, stream);
    embed_k<<<dim3(16384), dim3(256), 0, stream>>>(src, emb, X);
    wprep_k<<<dim3(12288), dim3(256), 0, stream>>>(Wih, Whh, Wt, probe);
    lstm_k<<<dim3(256), dim3(256), 0, stream>>>(X, Wt, bias, hbuf, out);
}